// Round 6
// baseline (108.121 us; speedup 1.0000x reference)
//
#include <hip/hip_runtime.h>

// NewSupConLoss: B=512, L=20, D=128. Gram N=10240, fused exp/rowsum.
// Round 6: spill-free hot loop. k_gram does ONLY exp-rowsum (numerator moved
// to fp32 side-path: g_c = sum_j lab_j f_j, W via dot in k_reduce).
// Grid (80 ta, 10 g): block = 128 rows x 1024 cols, stepped in 16 half-tiles
// of 64 cols (2x16KB LDS dbuf). 4 waves, wave = 64 rows x 32 cols:
// af persistent 64 VGPR + acc 32 AGPR + esum 16 -> ~135 regs, no spill.

#define NB 512
#define NL 20
#define NROW (NB * NL)            // 10240
#define FBYTES (NROW * 256)       // 2,621,440
#define SCALE 4.5398160f          // sqrt(log2(e)/0.07); dot feeds exp2 directly
#define TEMP_INV 14.285714285714286f

typedef float f32x4 __attribute__((ext_vector_type(4)));
typedef short short8 __attribute__((ext_vector_type(8)));
typedef unsigned short ushort4v __attribute__((ext_vector_type(4)));

static __device__ __forceinline__ unsigned short f2bf(float x) {
  unsigned int b = __float_as_uint(x);
  b += 0x7FFFu + ((b >> 16) & 1u);
  return (unsigned short)(b >> 16);
}

static __device__ __forceinline__ float fexp2(float x) {
#if __has_builtin(__builtin_amdgcn_exp2f)
  return __builtin_amdgcn_exp2f(x);
#else
  return exp2f(x);
#endif
}

// fp32 [B,L,D] -> bf16 rows a=l*512+i, scaled, XOR-swizzled per 256B row.
__global__ __launch_bounds__(256) void k_convert(const float* __restrict__ feat,
                                                 unsigned char* __restrict__ fswz) {
  int t = blockIdx.x * 256 + threadIdx.x;   // [0, 327680)
  int q = t & 31;
  int a = t >> 5;
  int l = a >> 9;
  int i = a & 511;
  const float* src = feat + (size_t)i * (NL * 128) + l * 128 + q * 4;
  float4 v = *(const float4*)src;
  ushort4v u;
  u.x = f2bf(v.x * SCALE); u.y = f2bf(v.y * SCALE);
  u.z = f2bf(v.z * SCALE); u.w = f2bf(v.w * SCALE);
  int dst = a * 256 + ((q * 8) ^ ((a & 7) << 4));
  *(ushort4v*)(fswz + dst) = u;
}

// g_c[c][d] = sum_i lab[i,c] * feat[i,c,d]  (fp32 exact)
__global__ __launch_bounds__(512) void k_gsum(const float* __restrict__ feat,
                                              const int* __restrict__ labels,
                                              float* __restrict__ gsum) {
  __shared__ float part[4][128];
  const int c = blockIdx.x;
  const int d = threadIdx.x & 127;
  const int iq = threadIdx.x >> 7;   // 0..3
  float s = 0.f;
#pragma unroll 8
  for (int i = iq * 128; i < iq * 128 + 128; ++i)
    s += labels[i * NL + c] ? feat[(size_t)i * (NL * 128) + c * 128 + d] : 0.f;
  part[iq][d] = s;
  __syncthreads();
  if (iq == 0) gsum[c * 128 + d] = part[0][d] + part[1][d] + part[2][d] + part[3][d];
}

// Pr[c][ta][wcg][r] : partial row-sums of exp over the wave's col slice.
__global__ __launch_bounds__(256) void k_gram(const unsigned char* __restrict__ fswz,
                                              float* __restrict__ Pr) {
  __shared__ unsigned char lds[32768];   // two 16KB half-tile buffers
  const int ta = blockIdx.x;             // row strip [ta*128, +128)
  const int g = blockIdx.y;              // cols [g*1024, +1024) = classes 2g,2g+1
  const int tid = threadIdx.x;
  const int lane = tid & 63, w = tid >> 6;   // 4 waves
  const int fr = lane & 15, kg = lane >> 4;
  const int wr = (w >> 1) * 64;          // 2 row groups of 64
  const int wcl = (w & 1) * 32;          // col offset within 64-col half-tile
  const int xr = (fr & 7) << 4;

  // ---- persistent A fragments: 16 x short8 = 64 VGPR ----
  short8 af[4][4];   // [kk][m]
#pragma unroll
  for (int kk = 0; kk < 4; ++kk)
#pragma unroll
    for (int m = 0; m < 4; ++m)
      af[kk][m] = *(const short8*)(fswz + (size_t)(ta * 128 + wr + m * 16 + fr) * 256 +
                                   ((kk * 64 + kg * 16) ^ xr));

  auto stage = [&](int buf, int ht) {    // ht in [0,16): half-tile of 64 rows
    const unsigned char* gB = fswz + (size_t)(g * 16 + ht) * 16384 + w * 4096 + lane * 16;
    unsigned char* lB = lds + buf * 16384 + w * 4096;   // wave-uniform base
#pragma unroll
    for (int p = 0; p < 4; ++p)
      __builtin_amdgcn_global_load_lds(
          (const __attribute__((address_space(1))) unsigned int*)(gB + p * 1024),
          (__attribute__((address_space(3))) unsigned int*)(lB + p * 1024), 16, 0, 0);
  };

  stage(0, 0);
  __syncthreads();

  float esum[4][4] = {};   // [m][reg]
  int cur = 0;

  for (int t = 0; t < 16; ++t) {
    if (t < 15) stage(cur ^ 1, t + 1);

    // ---- B frags + MFMA: wave computes 64x32 ----
    const unsigned char* lb = lds + cur * 16384;
    f32x4 acc[4][2] = {};
#pragma unroll
    for (int kk = 0; kk < 4; ++kk) {
      const int kb = (kk * 64 + kg * 16) ^ xr;
      short8 bf[2];
#pragma unroll
      for (int n = 0; n < 2; ++n)
        bf[n] = *(const short8*)(lb + (wcl + n * 16 + fr) * 256 + kb);
#pragma unroll
      for (int m = 0; m < 4; ++m)
#pragma unroll
        for (int n = 0; n < 2; ++n)
          acc[m][n] = __builtin_amdgcn_mfma_f32_16x16x32_bf16(af[kk][m], bf[n], acc[m][n], 0, 0, 0);
    }

    // ---- epilogue: exp + register accumulate ----
    const int tb = g * 8 + (t >> 1);
    const bool maskstep = ((tb & 3) == (ta & 3));   // diag (i==j) possible
    const int colbase = (t & 1) * 64 + wcl;

#define EPI(MASKED)                                                          \
  _Pragma("unroll") for (int m = 0; m < 4; ++m)                              \
  _Pragma("unroll") for (int reg = 0; reg < 4; ++reg) {                      \
    const int row_l = wr + m * 16 + kg * 4 + reg;                            \
    float e = 0.f;                                                           \
    _Pragma("unroll") for (int n = 0; n < 2; ++n) {                          \
      float ex = fexp2(acc[m][n][reg]);                                      \
      if (MASKED && row_l == colbase + n * 16 + fr) ex = 0.f;                \
      e += ex;                                                               \
    }                                                                        \
    esum[m][reg] += e;                                                       \
  }
    if (maskstep) { EPI(1) } else { EPI(0) }
#undef EPI

    // ---- class-boundary flush (t=7,15): shfl over fr + plain stores ----
    if ((t & 7) == 7) {
      const int c = g * 2 + (t >> 3);
#pragma unroll
      for (int m = 0; m < 4; ++m)
#pragma unroll
        for (int reg = 0; reg < 4; ++reg) {
          float e = esum[m][reg];
          e += __shfl_xor(e, 1, 64); e += __shfl_xor(e, 2, 64);
          e += __shfl_xor(e, 4, 64); e += __shfl_xor(e, 8, 64);
          if (fr == 0) {
            const int r = wr + m * 16 + kg * 4 + reg;   // 0..127
            Pr[((c * 80 + ta) * 2 + (w & 1)) * 128 + r] = e;
          }
          esum[m][reg] = 0.f;
        }
    }

    __syncthreads();   // staged buf ready; LDS reads of cur done
    cur ^= 1;
  }
}

// Slog[c][i] = log(sum of 40 Pr partials); wnum[c][i] = (f[c,i].g_c - 1)/T
__global__ __launch_bounds__(256) void k_reduce(const float* __restrict__ Pr,
                                               const float* __restrict__ feat,
                                               const float* __restrict__ gsum,
                                               float* __restrict__ Slog,
                                               float* __restrict__ wnum) {
  int idx = blockIdx.x * 256 + threadIdx.x;   // [0, 10240)
  int c = idx >> 9, i = idx & 511;
  float s = 0.f;
#pragma unroll
  for (int l2 = 0; l2 < NL; ++l2) {
    const float* p = Pr + ((c * 80 + (l2 * 4 + (i >> 7))) * 2) * 128 + (i & 127);
    s += p[0] + p[128];
  }
  Slog[idx] = logf(s);

  const float4* fp = (const float4*)(feat + (size_t)i * (NL * 128) + c * 128);
  const float4* gp = (const float4*)(gsum + c * 128);
  float wd = 0.f;
#pragma unroll
  for (int q = 0; q < 32; ++q) {
    float4 a = fp[q], b = gp[q];
    wd += a.x * b.x + a.y * b.y + a.z * b.z + a.w * b.w;
  }
  wnum[idx] = (wd - 1.f) * TEMP_INV;   // subtract self term f.f == 1 (normalized)
}

// Per-anchor combine + mean. One block, 512 threads.
__global__ __launch_bounds__(512) void k_final(const float* __restrict__ Slog,
                                               const float* __restrict__ wnum,
                                               const int* __restrict__ labels,
                                               float* __restrict__ out) {
  __shared__ float cnt[NL];
  __shared__ float red[8];
  const int i = threadIdx.x;
  if (i < NL) cnt[i] = 0.f;
  __syncthreads();
  int lab[NL];
#pragma unroll
  for (int cI = 0; cI < NL; ++cI) lab[cI] = labels[i * NL + cI];
#pragma unroll
  for (int cI = 0; cI < NL; ++cI)
    if (lab[cI]) atomicAdd(&cnt[cI], 1.f);
  __syncthreads();
  float avg = 0.f, acc = 0.f;
#pragma unroll
  for (int cI = 0; cI < NL; ++cI) {
    if (lab[cI]) {
      float wgt = cnt[cI] - 1.f;
      avg += wgt;
      acc += wnum[cI * NB + i] - wgt * Slog[cI * NB + i];
    }
  }
  float v = acc / (avg == 0.f ? 1.f : avg);
#pragma unroll
  for (int s = 1; s < 64; s <<= 1) v += __shfl_xor(v, s, 64);
  if ((i & 63) == 0) red[i >> 6] = v;
  __syncthreads();
  if (i == 0) {
    float tot = 0.f;
#pragma unroll
    for (int k = 0; k < 8; ++k) tot += red[k];
    out[0] = -(tot / (float)NB);
  }
}

extern "C" void kernel_launch(void* const* d_in, const int* in_sizes, int n_in,
                              void* d_out, int out_size, void* d_ws, size_t ws_size,
                              hipStream_t stream) {
  const float* feat = (const float*)d_in[0];
  const int* labels = (const int*)d_in[1];
  float* out = (float*)d_out;
  unsigned char* ws = (unsigned char*)d_ws;
  unsigned char* fswz = ws;
  float* Pr = (float*)(ws + FBYTES);     // 20*80*2*128 f32 = 1.6 MB
  float* gsum = Pr + 20 * 80 * 2 * 128;  // 20*128 f32
  float* Slog = gsum + 20 * 128;         // 10240 f32
  float* wnum = Slog + NROW;             // 10240 f32

  k_convert<<<NROW * 32 / 256, 256, 0, stream>>>(feat, fswz);
  k_gsum<<<NL, 512, 0, stream>>>(feat, labels, gsum);
  dim3 grid(80, 10);
  k_gram<<<grid, 256, 0, stream>>>(fswz, Pr);
  k_reduce<<<NROW / 256, 256, 0, stream>>>(Pr, feat, gsum, Slog, wnum);
  k_final<<<1, 512, 0, stream>>>(Slog, wnum, labels, out);
}

// Round 7
// 91.010 us; speedup vs baseline: 1.1880x; 1.1880x over previous
//
#include <hip/hip_runtime.h>

// NewSupConLoss: B=512, L=20, D=128. Gram N=10240, fused exp/rowsum.
// Round 7: side-path fixed (branchless gsum; coalesced wave-per-pair wnum),
// k_gram grid (80,20) for co-residency. Hot loop unchanged from round 6
// (spill-free: af 64 VGPR + acc 32 AGPR, 2x16KB LDS dbuf).

#define NB 512
#define NL 20
#define NROW (NB * NL)            // 10240
#define FBYTES (NROW * 256)       // 2,621,440
#define SCALE 4.5398160f          // sqrt(log2(e)/0.07); dot feeds exp2 directly
#define TEMP_INV 14.285714285714286f

typedef float f32x4 __attribute__((ext_vector_type(4)));
typedef short short8 __attribute__((ext_vector_type(8)));
typedef unsigned short ushort4v __attribute__((ext_vector_type(4)));

static __device__ __forceinline__ unsigned short f2bf(float x) {
  unsigned int b = __float_as_uint(x);
  b += 0x7FFFu + ((b >> 16) & 1u);
  return (unsigned short)(b >> 16);
}

static __device__ __forceinline__ float fexp2(float x) {
#if __has_builtin(__builtin_amdgcn_exp2f)
  return __builtin_amdgcn_exp2f(x);
#else
  return exp2f(x);
#endif
}

// fp32 [B,L,D] -> bf16 rows a=l*512+i, scaled, XOR-swizzled per 256B row.
__global__ __launch_bounds__(256) void k_convert(const float* __restrict__ feat,
                                                 unsigned char* __restrict__ fswz) {
  int t = blockIdx.x * 256 + threadIdx.x;   // [0, 327680)
  int q = t & 31;
  int a = t >> 5;
  int l = a >> 9;
  int i = a & 511;
  const float* src = feat + (size_t)i * (NL * 128) + l * 128 + q * 4;
  float4 v = *(const float4*)src;
  ushort4v u;
  u.x = f2bf(v.x * SCALE); u.y = f2bf(v.y * SCALE);
  u.z = f2bf(v.z * SCALE); u.w = f2bf(v.w * SCALE);
  int dst = a * 256 + ((q * 8) ^ ((a & 7) << 4));
  *(ushort4v*)(fswz + dst) = u;
}

// g_c[c][d] = sum_i lab[i,c] * feat[i,c,d]  (fp32, branchless)
__global__ __launch_bounds__(512) void k_gsum(const float* __restrict__ feat,
                                              const int* __restrict__ labels,
                                              float* __restrict__ gsum) {
  __shared__ float part[4][128];
  const int c = blockIdx.x;
  const int d = threadIdx.x & 127;
  const int iq = threadIdx.x >> 7;   // 0..3
  float s = 0.f;
#pragma unroll 8
  for (int i = iq * 128; i < iq * 128 + 128; ++i)
    s += (float)labels[i * NL + c] * feat[(size_t)i * (NL * 128) + c * 128 + d];
  part[iq][d] = s;
  __syncthreads();
  if (iq == 0) gsum[c * 128 + d] = part[0][d] + part[1][d] + part[2][d] + part[3][d];
}

// Pr[c][ta][half][r] : partial row-sums of exp over the wave's col slice.
// Grid (80 ta, 20 c): block = 128 rows x 512 cols (one class), 8 half-tiles.
__global__ __launch_bounds__(256) void k_gram(const unsigned char* __restrict__ fswz,
                                              float* __restrict__ Pr) {
  __shared__ unsigned char lds[32768];   // two 16KB half-tile buffers
  const int ta = blockIdx.x;             // row strip [ta*128, +128)
  const int g = blockIdx.y;              // class c = g; cols [g*512, +512)
  const int tid = threadIdx.x;
  const int lane = tid & 63, w = tid >> 6;   // 4 waves
  const int fr = lane & 15, kg = lane >> 4;
  const int wr = (w >> 1) * 64;          // 2 row groups of 64
  const int wcl = (w & 1) * 32;          // col offset within 64-col half-tile
  const int xr = (fr & 7) << 4;

  // ---- persistent A fragments: 16 x short8 = 64 VGPR ----
  short8 af[4][4];   // [kk][m]
#pragma unroll
  for (int kk = 0; kk < 4; ++kk)
#pragma unroll
    for (int m = 0; m < 4; ++m)
      af[kk][m] = *(const short8*)(fswz + (size_t)(ta * 128 + wr + m * 16 + fr) * 256 +
                                   ((kk * 64 + kg * 16) ^ xr));

  auto stage = [&](int buf, int t) {     // t in [0,8): half-tile of 64 rows
    const unsigned char* gB = fswz + (size_t)(g * 8 + t) * 16384 + w * 4096 + lane * 16;
    unsigned char* lB = lds + buf * 16384 + w * 4096;   // wave-uniform base
#pragma unroll
    for (int p = 0; p < 4; ++p)
      __builtin_amdgcn_global_load_lds(
          (const __attribute__((address_space(1))) unsigned int*)(gB + p * 1024),
          (__attribute__((address_space(3))) unsigned int*)(lB + p * 1024), 16, 0, 0);
  };

  stage(0, 0);
  __syncthreads();

  float esum[4][4] = {};   // [m][reg]
  int cur = 0;

#pragma unroll
  for (int t = 0; t < 8; ++t) {
    if (t < 7) stage(cur ^ 1, t + 1);

    // ---- B frags + MFMA: wave computes 64x32 ----
    const unsigned char* lb = lds + cur * 16384;
    f32x4 acc[4][2] = {};
#pragma unroll
    for (int kk = 0; kk < 4; ++kk) {
      const int kb = (kk * 64 + kg * 16) ^ xr;
      short8 bf[2];
#pragma unroll
      for (int n = 0; n < 2; ++n)
        bf[n] = *(const short8*)(lb + (wcl + n * 16 + fr) * 256 + kb);
#pragma unroll
      for (int m = 0; m < 4; ++m)
#pragma unroll
        for (int n = 0; n < 2; ++n)
          acc[m][n] = __builtin_amdgcn_mfma_f32_16x16x32_bf16(af[kk][m], bf[n], acc[m][n], 0, 0, 0);
    }

    // ---- epilogue: exp + register accumulate ----
    const bool maskstep = ((t >> 1) == (ta & 3));   // diag (i==j) possible
    const int colbase = (t & 1) * 64 + wcl;

#define EPI(MASKED)                                                          \
  _Pragma("unroll") for (int m = 0; m < 4; ++m)                              \
  _Pragma("unroll") for (int reg = 0; reg < 4; ++reg) {                      \
    const int row_l = wr + m * 16 + kg * 4 + reg;                            \
    float e = 0.f;                                                           \
    _Pragma("unroll") for (int n = 0; n < 2; ++n) {                          \
      float ex = fexp2(acc[m][n][reg]);                                      \
      if (MASKED && row_l == colbase + n * 16 + fr) ex = 0.f;                \
      e += ex;                                                               \
    }                                                                        \
    esum[m][reg] += e;                                                       \
  }
    if (maskstep) { EPI(1) } else { EPI(0) }
#undef EPI

    // ---- final flush (t=7): shfl over fr + plain stores ----
    if (t == 7) {
#pragma unroll
      for (int m = 0; m < 4; ++m)
#pragma unroll
        for (int reg = 0; reg < 4; ++reg) {
          float e = esum[m][reg];
          e += __shfl_xor(e, 1, 64); e += __shfl_xor(e, 2, 64);
          e += __shfl_xor(e, 4, 64); e += __shfl_xor(e, 8, 64);
          if (fr == 0) {
            const int r = wr + m * 16 + kg * 4 + reg;   // 0..127
            Pr[((g * 80 + ta) * 2 + (w & 1)) * 128 + r] = e;
          }
        }
    } else {
      __syncthreads();   // staged buf ready; LDS reads of cur done
      cur ^= 1;
    }
  }
}

// Merged: blocks [0,2560) compute wnum (wave per (c,i) pair, coalesced);
// blocks [2560,2600) compute Slog (coalesced Pr partial fold).
__global__ __launch_bounds__(256) void k_ws(const float* __restrict__ Pr,
                                            const float* __restrict__ feat,
                                            const float* __restrict__ gsum,
                                            float* __restrict__ Slog,
                                            float* __restrict__ wnum) {
  const int b = blockIdx.x;
  if (b < 2560) {
    const int lane = threadIdx.x & 63;
    const int p = b * 4 + (threadIdx.x >> 6);   // pair c*512+i
    const int c = p >> 9, i = p & 511;
    float2 f = *(const float2*)(feat + (size_t)i * (NL * 128) + c * 128 + lane * 2);
    float2 gv = *(const float2*)(gsum + c * 128 + lane * 2);
    float v = f.x * gv.x + f.y * gv.y;
#pragma unroll
    for (int s = 1; s < 64; s <<= 1) v += __shfl_xor(v, s, 64);
    if (lane == 0) wnum[p] = (v - 1.f) * TEMP_INV;   // subtract self term f.f==1
  } else {
    int idx = (b - 2560) * 256 + threadIdx.x;   // [0, 10240)
    int c = idx >> 9, i = idx & 511;
    float s = 0.f;
#pragma unroll
    for (int l2 = 0; l2 < NL; ++l2) {
      const float* p2 = Pr + ((c * 80 + (l2 * 4 + (i >> 7))) * 2) * 128 + (i & 127);
      s += p2[0] + p2[128];
    }
    Slog[idx] = logf(s);
  }
}

// Per-anchor combine + mean. One block, 512 threads.
__global__ __launch_bounds__(512) void k_final(const float* __restrict__ Slog,
                                               const float* __restrict__ wnum,
                                               const int* __restrict__ labels,
                                               float* __restrict__ out) {
  __shared__ float cnt[NL];
  __shared__ float red[8];
  const int i = threadIdx.x;
  if (i < NL) cnt[i] = 0.f;
  __syncthreads();
  int lab[NL];
#pragma unroll
  for (int cI = 0; cI < NL; ++cI) lab[cI] = labels[i * NL + cI];
#pragma unroll
  for (int cI = 0; cI < NL; ++cI)
    if (lab[cI]) atomicAdd(&cnt[cI], 1.f);
  __syncthreads();
  float avg = 0.f, acc = 0.f;
#pragma unroll
  for (int cI = 0; cI < NL; ++cI) {
    if (lab[cI]) {
      float wgt = cnt[cI] - 1.f;
      avg += wgt;
      acc += wnum[cI * NB + i] - wgt * Slog[cI * NB + i];
    }
  }
  float v = acc / (avg == 0.f ? 1.f : avg);
#pragma unroll
  for (int s = 1; s < 64; s <<= 1) v += __shfl_xor(v, s, 64);
  if ((i & 63) == 0) red[i >> 6] = v;
  __syncthreads();
  if (i == 0) {
    float tot = 0.f;
#pragma unroll
    for (int k = 0; k < 8; ++k) tot += red[k];
    out[0] = -(tot / (float)NB);
  }
}

extern "C" void kernel_launch(void* const* d_in, const int* in_sizes, int n_in,
                              void* d_out, int out_size, void* d_ws, size_t ws_size,
                              hipStream_t stream) {
  const float* feat = (const float*)d_in[0];
  const int* labels = (const int*)d_in[1];
  float* out = (float*)d_out;
  unsigned char* ws = (unsigned char*)d_ws;
  unsigned char* fswz = ws;
  float* Pr = (float*)(ws + FBYTES);     // 20*80*2*128 f32 = 1.6 MB
  float* gsum = Pr + 20 * 80 * 2 * 128;  // 20*128 f32
  float* Slog = gsum + 20 * 128;         // 10240 f32
  float* wnum = Slog + NROW;             // 10240 f32

  k_convert<<<NROW * 32 / 256, 256, 0, stream>>>(feat, fswz);
  k_gsum<<<NL, 512, 0, stream>>>(feat, labels, gsum);
  dim3 grid(80, 20);
  k_gram<<<grid, 256, 0, stream>>>(fswz, Pr);
  k_ws<<<2600, 256, 0, stream>>>(Pr, feat, gsum, Slog, wnum);
  k_final<<<1, 512, 0, stream>>>(Slog, wnum, labels, out);
}

// Round 8
// 80.066 us; speedup vs baseline: 1.3504x; 1.1367x over previous
//
#include <hip/hip_runtime.h>

// NewSupConLoss: B=512, L=20, D=128. Gram N=10240, fused exp/rowsum.
// Round 8: round-6 structure (grid 80x10, 16 subtile iters, spill-free) +
// triple-buffered stage pipeline: body(t) = {barrier; stage(t+2); compute(t)}
// so each barrier's vmcnt(0) drain targets loads issued one full compute
// phase earlier. No unroll on the t-loop (round 7's VGPR 140 regression).
// k_gsum merged into k_prep (one fewer launch).

#define NB 512
#define NL 20
#define NROW (NB * NL)            // 10240
#define FBYTES (NROW * 256)       // 2,621,440
#define SCALE 4.5398160f          // sqrt(log2(e)/0.07); dot feeds exp2 directly
#define TEMP_INV 14.285714285714286f

typedef float f32x4 __attribute__((ext_vector_type(4)));
typedef short short8 __attribute__((ext_vector_type(8)));
typedef unsigned short ushort4v __attribute__((ext_vector_type(4)));

static __device__ __forceinline__ unsigned short f2bf(float x) {
  unsigned int b = __float_as_uint(x);
  b += 0x7FFFu + ((b >> 16) & 1u);
  return (unsigned short)(b >> 16);
}

static __device__ __forceinline__ float fexp2(float x) {
#if __has_builtin(__builtin_amdgcn_exp2f)
  return __builtin_amdgcn_exp2f(x);
#else
  return exp2f(x);
#endif
}

// Blocks [0,1280): fp32 [B,L,D] -> bf16 rows a=l*512+i, scaled, XOR-swizzled.
// Blocks [1280,1300): g_c[c][d] = sum_i lab[i,c]*feat[i,c,d] (fp32, branchless).
__global__ __launch_bounds__(256) void k_prep(const float* __restrict__ feat,
                                              const int* __restrict__ labels,
                                              unsigned char* __restrict__ fswz,
                                              float* __restrict__ gsum) {
  if (blockIdx.x < 1280) {
    int t = blockIdx.x * 256 + threadIdx.x;   // [0, 327680)
    int q = t & 31;
    int a = t >> 5;
    int l = a >> 9;
    int i = a & 511;
    const float* src = feat + (size_t)i * (NL * 128) + l * 128 + q * 4;
    float4 v = *(const float4*)src;
    ushort4v u;
    u.x = f2bf(v.x * SCALE); u.y = f2bf(v.y * SCALE);
    u.z = f2bf(v.z * SCALE); u.w = f2bf(v.w * SCALE);
    int dst = a * 256 + ((q * 8) ^ ((a & 7) << 4));
    *(ushort4v*)(fswz + dst) = u;
  } else {
    __shared__ float part[2][128];
    const int c = blockIdx.x - 1280;
    const int d = threadIdx.x & 127;
    const int iq = threadIdx.x >> 7;   // 0..1
    float s = 0.f;
#pragma unroll 8
    for (int i = iq * 256; i < iq * 256 + 256; ++i)
      s += (float)labels[i * NL + c] * feat[(size_t)i * (NL * 128) + c * 128 + d];
    part[iq][d] = s;
    __syncthreads();
    if (iq == 0) gsum[c * 128 + d] = part[0][d] + part[1][d];
  }
}

// Pr[c][ta][half][r] : partial row-sums of exp over the wave's col slice.
// Grid (80 ta, 10 g): block = 128 rows x 1024 cols (classes 2g, 2g+1),
// 16 half-tiles of 64 cols, triple-buffered (3x16KB LDS).
__global__ __launch_bounds__(256) void k_gram(const unsigned char* __restrict__ fswz,
                                              float* __restrict__ Pr) {
  __shared__ unsigned char lds[49152];   // three 16KB half-tile buffers
  const int ta = blockIdx.x;             // row strip [ta*128, +128)
  const int g = blockIdx.y;              // cols [g*1024, +1024)
  const int tid = threadIdx.x;
  const int lane = tid & 63, w = tid >> 6;   // 4 waves
  const int fr = lane & 15, kg = lane >> 4;
  const int wr = (w >> 1) * 64;          // 2 row groups of 64
  const int wcl = (w & 1) * 32;          // col offset within 64-col half-tile
  const int xr = (fr & 7) << 4;

  // ---- persistent A fragments: 16 x short8 = 64 VGPR ----
  short8 af[4][4];   // [kk][m]
#pragma unroll
  for (int kk = 0; kk < 4; ++kk)
#pragma unroll
    for (int m = 0; m < 4; ++m)
      af[kk][m] = *(const short8*)(fswz + (size_t)(ta * 128 + wr + m * 16 + fr) * 256 +
                                   ((kk * 64 + kg * 16) ^ xr));

  auto stage = [&](int buf, int ht) {    // ht in [0,16): half-tile of 64 rows
    const unsigned char* gB = fswz + (size_t)(g * 16 + ht) * 16384 + w * 4096 + lane * 16;
    unsigned char* lB = lds + buf * 16384 + w * 4096;   // wave-uniform base
#pragma unroll
    for (int p = 0; p < 4; ++p)
      __builtin_amdgcn_global_load_lds(
          (const __attribute__((address_space(1))) unsigned int*)(gB + p * 1024),
          (__attribute__((address_space(3))) unsigned int*)(lB + p * 1024), 16, 0, 0);
  };

  // prologue: fill pipeline 2 deep
  stage(0, 0);
  stage(1, 1);

  float esum[4][4] = {};   // [m][reg]
  int cur = 0;             // buffer holding tile t

  for (int t = 0; t < 16; ++t) {
    // drain: waits stage(t+1) (issued one full compute phase ago; t=0: both)
    __syncthreads();
    if (t < 14) {
      int nb = cur + 2; if (nb >= 3) nb -= 3;
      stage(nb, t + 2);
    }

    // ---- B frags + MFMA: wave computes 64x32 from buf[cur] ----
    const unsigned char* lb = lds + cur * 16384;
    f32x4 acc[4][2] = {};
#pragma unroll
    for (int kk = 0; kk < 4; ++kk) {
      const int kb = (kk * 64 + kg * 16) ^ xr;
      short8 bf[2];
#pragma unroll
      for (int n = 0; n < 2; ++n)
        bf[n] = *(const short8*)(lb + (wcl + n * 16 + fr) * 256 + kb);
#pragma unroll
      for (int m = 0; m < 4; ++m)
#pragma unroll
        for (int n = 0; n < 2; ++n)
          acc[m][n] = __builtin_amdgcn_mfma_f32_16x16x32_bf16(af[kk][m], bf[n], acc[m][n], 0, 0, 0);
    }

    // ---- epilogue: exp + register accumulate ----
    const bool maskstep = (((t >> 1) & 3) == (ta & 3));   // diag (i==j) possible
    const int colbase = (t & 1) * 64 + wcl;

#define EPI(MASKED)                                                          \
  _Pragma("unroll") for (int m = 0; m < 4; ++m)                              \
  _Pragma("unroll") for (int reg = 0; reg < 4; ++reg) {                      \
    const int row_l = wr + m * 16 + kg * 4 + reg;                            \
    float e = 0.f;                                                           \
    _Pragma("unroll") for (int n = 0; n < 2; ++n) {                          \
      float ex = fexp2(acc[m][n][reg]);                                      \
      if (MASKED && row_l == colbase + n * 16 + fr) ex = 0.f;                \
      e += ex;                                                               \
    }                                                                        \
    esum[m][reg] += e;                                                       \
  }
    if (maskstep) { EPI(1) } else { EPI(0) }
#undef EPI

    // ---- class-boundary flush (t=7,15): shfl over fr + plain stores ----
    if ((t & 7) == 7) {
      const int c = g * 2 + (t >> 3);
#pragma unroll
      for (int m = 0; m < 4; ++m)
#pragma unroll
        for (int reg = 0; reg < 4; ++reg) {
          float e = esum[m][reg];
          e += __shfl_xor(e, 1, 64); e += __shfl_xor(e, 2, 64);
          e += __shfl_xor(e, 4, 64); e += __shfl_xor(e, 8, 64);
          if (fr == 0) {
            const int r = wr + m * 16 + kg * 4 + reg;   // 0..127
            Pr[((c * 80 + ta) * 2 + (w & 1)) * 128 + r] = e;
          }
          esum[m][reg] = 0.f;
        }
    }

    if (++cur == 3) cur = 0;
  }
}

// Blocks [0,2560): wnum (wave per (c,i) pair, coalesced);
// blocks [2560,2600): Slog (coalesced Pr partial fold).
__global__ __launch_bounds__(256) void k_ws(const float* __restrict__ Pr,
                                            const float* __restrict__ feat,
                                            const float* __restrict__ gsum,
                                            float* __restrict__ Slog,
                                            float* __restrict__ wnum) {
  const int b = blockIdx.x;
  if (b < 2560) {
    const int lane = threadIdx.x & 63;
    const int p = b * 4 + (threadIdx.x >> 6);   // pair c*512+i
    const int c = p >> 9, i = p & 511;
    float2 f = *(const float2*)(feat + (size_t)i * (NL * 128) + c * 128 + lane * 2);
    float2 gv = *(const float2*)(gsum + c * 128 + lane * 2);
    float v = f.x * gv.x + f.y * gv.y;
#pragma unroll
    for (int s = 1; s < 64; s <<= 1) v += __shfl_xor(v, s, 64);
    if (lane == 0) wnum[p] = (v - 1.f) * TEMP_INV;   // subtract self term f.f==1
  } else {
    int idx = (b - 2560) * 256 + threadIdx.x;   // [0, 10240)
    int c = idx >> 9, i = idx & 511;
    float s = 0.f;
#pragma unroll
    for (int l2 = 0; l2 < NL; ++l2) {
      const float* p2 = Pr + ((c * 80 + (l2 * 4 + (i >> 7))) * 2) * 128 + (i & 127);
      s += p2[0] + p2[128];
    }
    Slog[idx] = logf(s);
  }
}

// Per-anchor combine + mean. One block, 512 threads.
__global__ __launch_bounds__(512) void k_final(const float* __restrict__ Slog,
                                               const float* __restrict__ wnum,
                                               const int* __restrict__ labels,
                                               float* __restrict__ out) {
  __shared__ float cnt[NL];
  __shared__ float red[8];
  const int i = threadIdx.x;
  if (i < NL) cnt[i] = 0.f;
  __syncthreads();
  int lab[NL];
#pragma unroll
  for (int cI = 0; cI < NL; ++cI) lab[cI] = labels[i * NL + cI];
#pragma unroll
  for (int cI = 0; cI < NL; ++cI)
    if (lab[cI]) atomicAdd(&cnt[cI], 1.f);
  __syncthreads();
  float avg = 0.f, acc = 0.f;
#pragma unroll
  for (int cI = 0; cI < NL; ++cI) {
    if (lab[cI]) {
      float wgt = cnt[cI] - 1.f;
      avg += wgt;
      acc += wnum[cI * NB + i] - wgt * Slog[cI * NB + i];
    }
  }
  float v = acc / (avg == 0.f ? 1.f : avg);
#pragma unroll
  for (int s = 1; s < 64; s <<= 1) v += __shfl_xor(v, s, 64);
  if ((i & 63) == 0) red[i >> 6] = v;
  __syncthreads();
  if (i == 0) {
    float tot = 0.f;
#pragma unroll
    for (int k = 0; k < 8; ++k) tot += red[k];
    out[0] = -(tot / (float)NB);
  }
}

extern "C" void kernel_launch(void* const* d_in, const int* in_sizes, int n_in,
                              void* d_out, int out_size, void* d_ws, size_t ws_size,
                              hipStream_t stream) {
  const float* feat = (const float*)d_in[0];
  const int* labels = (const int*)d_in[1];
  float* out = (float*)d_out;
  unsigned char* ws = (unsigned char*)d_ws;
  unsigned char* fswz = ws;
  float* Pr = (float*)(ws + FBYTES);     // 20*80*2*128 f32 = 1.6 MB
  float* gsum = Pr + 20 * 80 * 2 * 128;  // 20*128 f32
  float* Slog = gsum + 20 * 128;         // 10240 f32
  float* wnum = Slog + NROW;             // 10240 f32

  k_prep<<<1300, 256, 0, stream>>>(feat, labels, fswz, gsum);
  dim3 grid(80, 10);
  k_gram<<<grid, 256, 0, stream>>>(fswz, Pr);
  k_ws<<<2600, 256, 0, stream>>>(Pr, feat, gsum, Slog, wnum);
  k_final<<<1, 512, 0, stream>>>(Slog, wnum, labels, out);
}

// Round 9
// 74.535 us; speedup vs baseline: 1.4506x; 1.0742x over previous
//
#include <hip/hip_runtime.h>

// NewSupConLoss: B=512, L=20, D=128. Gram N=10240, fused exp/rowsum.
// Round 9: barrier-free wave-granular pipeline. 1 wave per block (64 thr),
// wave = 64 rows x 512 cols (one class) stepped in 32 slices of 16 cols.
// Wave-private 2x4KB LDS double buffer, synced by counted s_waitcnt vmcnt(4)
// only (vmem retires in order within a wave) -> zero barriers, 3200
// independent waves, ~16 waves/CU resident.

#define NB 512
#define NL 20
#define NROW (NB * NL)            // 10240
#define FBYTES (NROW * 256)       // 2,621,440
#define SCALE 4.5398160f          // sqrt(log2(e)/0.07); dot feeds exp2 directly
#define TEMP_INV 14.285714285714286f

typedef float f32x4 __attribute__((ext_vector_type(4)));
typedef short short8 __attribute__((ext_vector_type(8)));
typedef unsigned short ushort4v __attribute__((ext_vector_type(4)));

static __device__ __forceinline__ unsigned short f2bf(float x) {
  unsigned int b = __float_as_uint(x);
  b += 0x7FFFu + ((b >> 16) & 1u);
  return (unsigned short)(b >> 16);
}

static __device__ __forceinline__ float fexp2(float x) {
#if __has_builtin(__builtin_amdgcn_exp2f)
  return __builtin_amdgcn_exp2f(x);
#else
  return exp2f(x);
#endif
}

// Blocks [0,1280): fp32 [B,L,D] -> bf16 rows a=l*512+i, scaled, XOR-swizzled.
// Blocks [1280,1300): g_c[c][d] = sum_i lab[i,c]*feat[i,c,d] (fp32, branchless).
__global__ __launch_bounds__(256) void k_prep(const float* __restrict__ feat,
                                              const int* __restrict__ labels,
                                              unsigned char* __restrict__ fswz,
                                              float* __restrict__ gsum) {
  if (blockIdx.x < 1280) {
    int t = blockIdx.x * 256 + threadIdx.x;   // [0, 327680)
    int q = t & 31;
    int a = t >> 5;
    int l = a >> 9;
    int i = a & 511;
    const float* src = feat + (size_t)i * (NL * 128) + l * 128 + q * 4;
    float4 v = *(const float4*)src;
    ushort4v u;
    u.x = f2bf(v.x * SCALE); u.y = f2bf(v.y * SCALE);
    u.z = f2bf(v.z * SCALE); u.w = f2bf(v.w * SCALE);
    int dst = a * 256 + ((q * 8) ^ ((a & 7) << 4));
    *(ushort4v*)(fswz + dst) = u;
  } else {
    __shared__ float part[2][128];
    const int c = blockIdx.x - 1280;
    const int d = threadIdx.x & 127;
    const int iq = threadIdx.x >> 7;   // 0..1
    float s = 0.f;
#pragma unroll 8
    for (int i = iq * 256; i < iq * 256 + 256; ++i)
      s += (float)labels[i * NL + c] * feat[(size_t)i * (NL * 128) + c * 128 + d];
    part[iq][d] = s;
    __syncthreads();
    if (iq == 0) gsum[c * 128 + d] = part[0][d] + part[1][d];
  }
}

// Pr[c][sr][r] : partial row-sums of exp for 64-row strip sr over class c.
// Grid (160 sr, 20 c), 64 threads (1 wave).
__global__ __launch_bounds__(64) void k_gram(const unsigned char* __restrict__ fswz,
                                             float* __restrict__ Pr) {
  __shared__ unsigned char lds[8192];    // two wave-private 4KB slice buffers
  const int sr = blockIdx.x;             // row strip [sr*64, +64)
  const int c = blockIdx.y;              // class: cols [c*512, +512)
  const int lane = threadIdx.x;          // 0..63
  const int fr = lane & 15, kg = lane >> 4;
  const int xr = (fr & 7) << 4;

  // ---- persistent A fragments: 16 x short8 = 64 VGPR ----
  short8 af[4][4];   // [kk][m]
#pragma unroll
  for (int kk = 0; kk < 4; ++kk)
#pragma unroll
    for (int m = 0; m < 4; ++m)
      af[kk][m] = *(const short8*)(fswz + (size_t)(sr * 64 + m * 16 + fr) * 256 +
                                   ((kk * 64 + kg * 16) ^ xr));

  auto stage = [&](int buf, int t) {     // slice t: 16 Gram-cols = 4KB contiguous
    const unsigned char* g = fswz + ((size_t)c * 512 + t * 16) * 256 + lane * 16;
    unsigned char* l = lds + buf * 4096 + lane * 16;
#pragma unroll
    for (int p = 0; p < 2; ++p) {
      __builtin_amdgcn_global_load_lds(
          (const __attribute__((address_space(1))) unsigned int*)(g + p * 1024),
          (__attribute__((address_space(3))) unsigned int*)(l + p * 1024), 16, 0, 0);
      __builtin_amdgcn_global_load_lds(
          (const __attribute__((address_space(1))) unsigned int*)(g + p * 1024 + 2048),
          (__attribute__((address_space(3))) unsigned int*)(l + p * 1024 + 2048), 16, 0, 0);
    }
  };

  stage(0, 0);
  float esum[4][4] = {};   // [m][reg]

  for (int t = 0; t < 32; ++t) {
    // compile-time fence: keep this iteration's stage below last iter's ds_reads
    asm volatile("" ::: "memory");
    if (t < 31) {
      stage((t + 1) & 1, t + 1);
      asm volatile("s_waitcnt vmcnt(4)" ::: "memory");   // slice t resident
    } else {
      asm volatile("s_waitcnt vmcnt(0)" ::: "memory");
    }

    const unsigned char* lb = lds + (t & 1) * 4096;
    f32x4 acc[4] = {};   // wave computes 64 rows x 16 cols
#pragma unroll
    for (int kk = 0; kk < 4; ++kk) {
      short8 bf = *(const short8*)(lb + fr * 256 + ((kk * 64 + kg * 16) ^ xr));
#pragma unroll
      for (int m = 0; m < 4; ++m)
        acc[m] = __builtin_amdgcn_mfma_f32_16x16x32_bf16(af[kk][m], bf, acc[m], 0, 0, 0);
    }

    // ---- epilogue: exp + accumulate (diag masked where i==j) ----
    const bool maskstep = ((t >> 2) == (sr & 7));
    const int mt = t & 3;
#pragma unroll
    for (int m = 0; m < 4; ++m)
#pragma unroll
      for (int reg = 0; reg < 4; ++reg) {
        float ex = fexp2(acc[m][reg]);
        if (maskstep && m == mt && (kg * 4 + reg) == fr) ex = 0.f;
        esum[m][reg] += ex;
      }
  }

  // ---- flush once: reduce over fr (16 cols) + plain stores ----
#pragma unroll
  for (int m = 0; m < 4; ++m)
#pragma unroll
    for (int reg = 0; reg < 4; ++reg) {
      float e = esum[m][reg];
      e += __shfl_xor(e, 1, 64); e += __shfl_xor(e, 2, 64);
      e += __shfl_xor(e, 4, 64); e += __shfl_xor(e, 8, 64);
      if (fr == 0)
        Pr[((size_t)c * 160 + sr) * 64 + m * 16 + kg * 4 + reg] = e;
    }
}

// Blocks [0,2560): wnum (wave per (c,i) pair, coalesced);
// blocks [2560,2600): Slog (coalesced Pr partial fold).
__global__ __launch_bounds__(256) void k_ws(const float* __restrict__ Pr,
                                            const float* __restrict__ feat,
                                            const float* __restrict__ gsum,
                                            float* __restrict__ Slog,
                                            float* __restrict__ wnum) {
  const int b = blockIdx.x;
  if (b < 2560) {
    const int lane = threadIdx.x & 63;
    const int p = b * 4 + (threadIdx.x >> 6);   // pair c*512+i
    const int c = p >> 9, i = p & 511;
    float2 f = *(const float2*)(feat + (size_t)i * (NL * 128) + c * 128 + lane * 2);
    float2 gv = *(const float2*)(gsum + c * 128 + lane * 2);
    float v = f.x * gv.x + f.y * gv.y;
#pragma unroll
    for (int s = 1; s < 64; s <<= 1) v += __shfl_xor(v, s, 64);
    if (lane == 0) wnum[p] = (v - 1.f) * TEMP_INV;   // subtract self term f.f==1
  } else {
    int idx = (b - 2560) * 256 + threadIdx.x;   // [0, 10240)
    int c = idx >> 9, i = idx & 511;
    float s = 0.f;
#pragma unroll
    for (int l2 = 0; l2 < NL; ++l2)
      s += Pr[((size_t)c * 160 + l2 * 8 + (i >> 6)) * 64 + (i & 63)];
    Slog[idx] = logf(s);
  }
}

// Per-anchor combine + mean. One block, 512 threads.
__global__ __launch_bounds__(512) void k_final(const float* __restrict__ Slog,
                                               const float* __restrict__ wnum,
                                               const int* __restrict__ labels,
                                               float* __restrict__ out) {
  __shared__ float cnt[NL];
  __shared__ float red[8];
  const int i = threadIdx.x;
  if (i < NL) cnt[i] = 0.f;
  __syncthreads();
  int lab[NL];
#pragma unroll
  for (int cI = 0; cI < NL; ++cI) lab[cI] = labels[i * NL + cI];
#pragma unroll
  for (int cI = 0; cI < NL; ++cI)
    if (lab[cI]) atomicAdd(&cnt[cI], 1.f);
  __syncthreads();
  float avg = 0.f, acc = 0.f;
#pragma unroll
  for (int cI = 0; cI < NL; ++cI) {
    if (lab[cI]) {
      float wgt = cnt[cI] - 1.f;
      avg += wgt;
      acc += wnum[cI * NB + i] - wgt * Slog[cI * NB + i];
    }
  }
  float v = acc / (avg == 0.f ? 1.f : avg);
#pragma unroll
  for (int s = 1; s < 64; s <<= 1) v += __shfl_xor(v, s, 64);
  if ((i & 63) == 0) red[i >> 6] = v;
  __syncthreads();
  if (i == 0) {
    float tot = 0.f;
#pragma unroll
    for (int k = 0; k < 8; ++k) tot += red[k];
    out[0] = -(tot / (float)NB);
  }
}

extern "C" void kernel_launch(void* const* d_in, const int* in_sizes, int n_in,
                              void* d_out, int out_size, void* d_ws, size_t ws_size,
                              hipStream_t stream) {
  const float* feat = (const float*)d_in[0];
  const int* labels = (const int*)d_in[1];
  float* out = (float*)d_out;
  unsigned char* ws = (unsigned char*)d_ws;
  unsigned char* fswz = ws;
  float* Pr = (float*)(ws + FBYTES);     // 20*160*64 f32 = 819 KB
  float* gsum = Pr + 20 * 160 * 64;      // 20*128 f32
  float* Slog = gsum + 20 * 128;         // 10240 f32
  float* wnum = Slog + NROW;             // 10240 f32

  k_prep<<<1300, 256, 0, stream>>>(feat, labels, fswz, gsum);
  dim3 grid(160, 20);
  k_gram<<<grid, 64, 0, stream>>>(fswz, Pr);
  k_ws<<<2600, 256, 0, stream>>>(Pr, feat, gsum, Slog, wnum);
  k_final<<<1, 512, 0, stream>>>(Slog, wnum, labels, out);
}